// Round 4
// baseline (373.754 us; speedup 1.0000x reference)
//
#include <hip/hip_runtime.h>
#include <hip/hip_cooperative_groups.h>
#include <math.h>

namespace cg = cooperative_groups;

#define NB 4
#define LQ 512
#define LK 512
#define DM 512
#define NH 8
#define DQ 64
#define NL 8
#define QT 32          // q-rows per attn block
#define PSTR 520       // Ps row stride in shorts (260 dwords % 32 = 4 -> 2-way max)

// shared-memory layout (bytes) -- union of all phases, 78336 B total
#define SM_QS   0          // 4096   Qs[32*64] shorts
#define SM_KC   4096       // 32768  Kc[2][128*64] shorts (also proj As/Bs region)
#define SM_PS   36864      // 33280  Ps[32*520] shorts
#define SM_SV   70144      // 1024   svS[32*8] float
#define SM_LUT  71168      // 4096   lutS[32*32] float
#define SM_TS   75264      // 1024   tS[32*8] float
#define SM_RA   76288      // 1024   redA
#define SM_RB   77312      // 1024   redB
#define SM_TOTAL 78336

typedef short bf16x8 __attribute__((ext_vector_type(8)));
typedef _Float16 f16x8 __attribute__((ext_vector_type(8)));
typedef _Float16 f16x2 __attribute__((ext_vector_type(2)));
typedef float f32x4 __attribute__((ext_vector_type(4)));

__device__ __forceinline__ unsigned short f2bf(float x) {
    unsigned u = __float_as_uint(x);
    u += 0x7fff + ((u >> 16) & 1);          // RNE
    return (unsigned short)(u >> 16);
}
__device__ __forceinline__ float bf2f(unsigned x) {
    return __uint_as_float(x << 16);
}
__device__ __forceinline__ unsigned short f2h(float x) {
    _Float16 h = (_Float16)x;               // v_cvt_f16_f32 (RNE)
    return __builtin_bit_cast(unsigned short, h);
}
// async global->LDS, 16B/lane; LDS dest = wave-uniform base + lane*16
__device__ __forceinline__ void gld16(const void* g, void* l) {
    __builtin_amdgcn_global_load_lds(
        (const __attribute__((address_space(1))) void*)g,
        (__attribute__((address_space(3))) void*)l, 16, 0, 0);
}

#define WAITVM(N) asm volatile("s_waitcnt vmcnt(" #N ")" ::: "memory")
#define LGKM0()   asm volatile("s_waitcnt lgkmcnt(0)" ::: "memory")
#define BARR()    do { asm volatile("" ::: "memory"); \
                       __builtin_amdgcn_s_barrier();  \
                       asm volatile("" ::: "memory"); } while (0)

// ===========================================================================
// Shared phase bodies
// ===========================================================================

// ---- prep work items (used by both paths) ---------------------------------
__device__ __forceinline__ void conv_vec8(const float* __restrict__ s,
                                          unsigned short* __restrict__ d, int i) {
    const float4* sv = (const float4*)s;
    const float4 a = sv[2 * (size_t)i], b = sv[2 * (size_t)i + 1];
    uint4 o;
    o.x = (unsigned)f2bf(a.x) | ((unsigned)f2bf(a.y) << 16);
    o.y = (unsigned)f2bf(a.z) | ((unsigned)f2bf(a.w) << 16);
    o.z = (unsigned)f2bf(b.x) | ((unsigned)f2bf(b.y) << 16);
    o.w = (unsigned)f2bf(b.z) | ((unsigned)f2bf(b.w) << 16);
    *(uint4*)(d + (size_t)i * 8) = o;
}
__device__ __forceinline__ void pack_pk(const float* __restrict__ em,
                                        const float* __restrict__ pad,
                                        unsigned short* __restrict__ Pk,
                                        int row, int k0) {
    const float* eb = em + ((size_t)row * LK + k0) * NL;
    const float4 pv0 = *(const float4*)(pad + (size_t)row * LK + k0);
    const float4 pv1 = *(const float4*)(pad + (size_t)row * LK + k0 + 4);
    const float pv[8] = {pv0.x, pv0.y, pv0.z, pv0.w, pv1.x, pv1.y, pv1.z, pv1.w};
    unsigned short outv[8];
#pragma unroll
    for (int kk = 0; kk < 8; ++kk) {
        const float4 v0 = *(const float4*)(eb + kk * 8);
        const float4 v1 = *(const float4*)(eb + kk * 8 + 4);
        unsigned b_ = 0;
        b_ |= (v0.x != 0.f) << 0; b_ |= (v0.y != 0.f) << 1;
        b_ |= (v0.z != 0.f) << 2; b_ |= (v0.w != 0.f) << 3;
        b_ |= (v1.x != 0.f) << 4; b_ |= (v1.y != 0.f) << 5;
        b_ |= (v1.z != 0.f) << 6; b_ |= (v1.w != 0.f) << 7;
        b_ |= (pv[kk] != 0.f) << 8;
        outv[kk] = (unsigned short)b_;
    }
    uint4 o;
    o.x = (unsigned)outv[0] | ((unsigned)outv[1] << 16);
    o.y = (unsigned)outv[2] | ((unsigned)outv[3] << 16);
    o.z = (unsigned)outv[4] | ((unsigned)outv[5] << 16);
    o.w = (unsigned)outv[6] | ((unsigned)outv[7] << 16);
    *(uint4*)(Pk + (size_t)row * LK + k0) = o;
}

// ---- 8-wave macro-GEMM: C(64 x 128) = A(64xK) * B(128xK)^T, K=512, BK=32 --
// waves 0-3 stage A (1KB each) + B rows (1KB each); waves 4-7 stage B only.
// counted vmcnt double-buffer (wave<4: 2 ops/step, wave>=4: 1 op/step).
// MODE: 0 = bf16 store (+opt bias), 1 = Vt f16 transposed, 2 = fp32 + bias.
template<int MODE>
__device__ void gemm_macro(const unsigned short* __restrict__ Ag,
                           const unsigned short* __restrict__ Bg,
                           const float* __restrict__ bias,
                           void* __restrict__ Cp,
                           int m0, int n0p, char* smemc) {
    short* As = (short*)(smemc);            // [2][64*32]  = 8192 B
    short* Bs = (short*)(smemc + 8192);     // [2][128*32] = 16384 B
    const int tid = threadIdx.x;
    const int wave = tid >> 6, lane = tid & 63;
    const int quad = lane >> 4, l16 = lane & 15;
    const int wl = wave & 3, wh = wave >> 2;
    const int wr = wl >> 1, wc = wl & 1;
    f32x4 acc[2][2];
    const f32x4 zz = {0.f, 0.f, 0.f, 0.f};
#pragma unroll
    for (int i = 0; i < 2; ++i)
#pragma unroll
        for (int j = 0; j < 2; ++j) acc[i][j] = zz;
    const int ar = lane >> 2, ac = (lane & 3) * 8;
    const unsigned short* Arp = Ag + (size_t)(m0 + wave * 16 + ar) * DM + ac;   // wave<4
    const unsigned short* Brp = Bg + (size_t)(n0p + wave * 16 + ar) * DM + ac;  // all
    if (wave < 4) gld16(Arp, (char*)As + wave * 1024);
    gld16(Brp, (char*)Bs + wave * 1024);
#pragma unroll
    for (int s = 0; s < 16; ++s) {
        if (s < 15) {
            const int nb = (s + 1) & 1;
            if (wave < 4) {
                gld16(Arp + (s + 1) * 32, (char*)As + nb * 4096 + wave * 1024);
                gld16(Brp + (s + 1) * 32, (char*)Bs + nb * 8192 + wave * 1024);
                WAITVM(2);
            } else {
                gld16(Brp + (s + 1) * 32, (char*)Bs + nb * 8192 + wave * 1024);
                WAITVM(1);
            }
        } else {
            WAITVM(0);
        }
        BARR();
        const int cb = s & 1;
        bf16x8 af[2], bf[2];
#pragma unroll
        for (int i = 0; i < 2; ++i)
            af[i] = *(const bf16x8*)&As[cb * 2048 + (wr * 32 + i * 16 + l16) * 32 + quad * 8];
#pragma unroll
        for (int j = 0; j < 2; ++j)
            bf[j] = *(const bf16x8*)&Bs[cb * 4096 + (wh * 64 + wc * 32 + j * 16 + l16) * 32 + quad * 8];
#pragma unroll
        for (int i = 0; i < 2; ++i)
#pragma unroll
            for (int j = 0; j < 2; ++j)
                acc[i][j] = __builtin_amdgcn_mfma_f32_16x16x32_bf16(af[i], bf[j], acc[i][j], 0, 0, 0);
        BARR();
    }
#pragma unroll
    for (int i = 0; i < 2; ++i)
#pragma unroll
        for (int r = 0; r < 4; ++r) {
            const int gm = m0 + wr * 32 + i * 16 + quad * 4 + r;
#pragma unroll
            for (int j = 0; j < 2; ++j) {
                const int gn = n0p + wh * 64 + wc * 32 + j * 16 + l16;
                float v = acc[i][j][r];
                if (MODE == 0) {
                    if (bias) v += bias[gn];
                    ((unsigned short*)Cp)[(size_t)gm * DM + gn] = f2bf(v);
                } else if (MODE == 1) {
                    ((unsigned short*)Cp)[(size_t)(gm >> 9) * (DM * LK)
                                          + (size_t)gn * LK + (gm & 511)] = f2h(v);
                } else {
                    ((float*)Cp)[(size_t)gm * DM + gn] = v + bias[gn];
                }
            }
        }
}

// ---- fused attention body (identical logic to the verified round-3 kernel),
// parameterized on the tile (xq) and z = h*4+b so it can be called from both
// the standalone kernel and the cooperative mega-kernel.
#define KC(hb) ((short*)(smemc + SM_KC + (hb) * 16384))

#define STAGE_K(c, hb) do {                                                       \
    _Pragma("unroll")                                                             \
    for (int it_ = 0; it_ < 2; ++it_) {                                           \
        const int e_ = it_ * 512 + tid;                                           \
        const int kr_ = e_ >> 3, ch_ = e_ & 7;                                    \
        gld16(Kp + (size_t)(b * LK + (c) * 128 + kr_) * DM + h * DQ               \
                  + ((ch_ ^ (kr_ & 7)) * 8),                                      \
              (char*)KC(hb) + it_ * 8192 + wave * 1024);                          \
    } } while (0)

#define STAGE_V(vc, hb) do {                                                      \
    _Pragma("unroll")                                                             \
    for (int it_ = 0; it_ < 2; ++it_) {                                           \
        const int e_ = it_ * 512 + tid;                                           \
        const int dd_ = e_ >> 4, ch_ = e_ & 15;                                   \
        gld16(Vt + (size_t)(b * DM + h * DQ + dd_) * LK + (vc) * 128              \
                  + ((ch_ ^ (dd_ & 15)) * 8),                                     \
              (char*)KC(hb) + it_ * 8192 + wave * 1024);                          \
    } } while (0)

#define COMPUTE_K(c, hb) do {                                                     \
    _Pragma("unroll")                                                             \
    for (int kdi_ = 0; kdi_ < 2; ++kdi_) {                                        \
        const int krow_ = wave * 16 + l16;                                        \
        const int kch_ = (kdi_ * 4 + quad) ^ (krow_ & 7);                         \
        const bf16x8 bfv_ = *(const bf16x8*)&KC(hb)[krow_ * 64 + kch_ * 8];       \
        acc[c][0] = __builtin_amdgcn_mfma_f32_16x16x32_bf16(qf[0][kdi_], bfv_,    \
                                                            acc[c][0], 0, 0, 0); \
        acc[c][1] = __builtin_amdgcn_mfma_f32_16x16x32_bf16(qf[1][kdi_], bfv_,    \
                                                            acc[c][1], 0, 0, 0); \
    } } while (0)

#define COMPUTE_V(vc, hb) do {                                                    \
    _Pragma("unroll")                                                             \
    for (int kd_ = 0; kd_ < 128; kd_ += 32) {                                     \
        const int vrow_ = ni * 16 + l16;                                          \
        const int vch_ = ((kd_ >> 3) + quad) ^ (vrow_ & 15);                      \
        const f16x8 afv_ = *(const f16x8*)&Ps[(mi * 16 + l16) * PSTR              \
                                              + (vc) * 128 + kd_ + quad * 8];     \
        const f16x8 bfv_ = *(const f16x8*)&KC(hb)[vrow_ * 128 + vch_ * 8];        \
        oacc = __builtin_amdgcn_mfma_f32_16x16x32_f16(afv_, bfv_, oacc, 0, 0, 0); \
    } } while (0)

__device__ void attn_body(char* smemc, const int xq, const int z,
        const unsigned short* __restrict__ Qp,
        const unsigned short* __restrict__ Kp,
        const unsigned short* __restrict__ Vt,     // f16 [b][d][k]
        const unsigned short* __restrict__ Pk,
        const float* __restrict__ b_ks,
        const float* __restrict__ b_vs,
        float* __restrict__ weights,
        unsigned short* __restrict__ Hb) {
    short* Qs   = (short*)(smemc + SM_QS);
    short* Ps   = (short*)(smemc + SM_PS);
    float* svS  = (float*)(smemc + SM_SV);
    float* lutS = (float*)(smemc + SM_LUT);
    float* tS   = (float*)(smemc + SM_TS);
    float* redA = (float*)(smemc + SM_RA);
    float* redB = (float*)(smemc + SM_RB);

    const int tid = threadIdx.x, wave = tid >> 6, lane = tid & 63;
    const int quad = lane >> 4, l16 = lane & 15;
    const int q0 = xq * QT;
    const int h = z >> 2, b = z & 3;

    // ---- svS source loads (issued before the stages in program order) ----
    const int srow = tid >> 4, sl = (tid >> 1) & 7, shalf = tid & 1;
    bf16x8 sq[4];
    {
        const unsigned short* qrow = Qp + (size_t)(b * LQ + q0 + srow) * DM + h * DQ + shalf * 32;
#pragma unroll
        for (int d0 = 0; d0 < 4; ++d0) sq[d0] = *(const bf16x8*)&qrow[d0 * 8];
    }

    // ---- stage Q tile (swizzled) + K0/K1 double-buffer prologue ----
    if (tid < 256) {
        const int row = tid >> 3, ch = tid & 7;
        gld16(Qp + (size_t)(b * LQ + q0 + row) * DM + h * DQ + ((ch ^ (row & 7)) * 8),
              (char*)Qs + wave * 1024);
    }
    STAGE_K(0, 0);
    STAGE_K(1, 1);

    // ---- svS[row][l] = sum_d Q[row][d] * b_ks[l][d] (register data) ----
    {
        const float* bk = b_ks + sl * DQ + shalf * 32;
        float s = 0.f;
#pragma unroll
        for (int d0 = 0; d0 < 4; ++d0)
#pragma unroll
            for (int j = 0; j < 8; ++j)
                s = fmaf(bf2f((unsigned short)sq[d0][j]), bk[d0 * 8 + j], s);
        s += __shfl_xor(s, 1, 64);
        if (shalf == 0) svS[srow * 8 + sl] = s;
    }

    f32x4 acc[4][2];
    const f32x4 zz = {0.f, 0.f, 0.f, 0.f};
#pragma unroll
    for (int c = 0; c < 4; ++c) { acc[c][0] = zz; acc[c][1] = zz; }
    bf16x8 qf[2][2];

    // ================= K pipeline =================
    WAITVM(2); LGKM0(); BARR();
#pragma unroll
    for (int i = 0; i < 2; ++i)
#pragma unroll
        for (int kdi = 0; kdi < 2; ++kdi)
            qf[i][kdi] = *(const bf16x8*)&Qs[(i * 16 + l16) * 64
                                             + (((kdi * 4) + quad) ^ (l16 & 7)) * 8];
#pragma unroll
    for (int e2 = 0; e2 < 2; ++e2) {
        const int e = e2 * 512 + tid;
        const int row = e >> 5, idx = e & 31;
        const float* sp = &svS[row * 8 + ((idx & 16) ? 4 : 0)];
        float v = 0.f;
        v += (idx & 1) ? sp[0] : 0.f;
        v += (idx & 2) ? sp[1] : 0.f;
        v += (idx & 4) ? sp[2] : 0.f;
        v += (idx & 8) ? sp[3] : 0.f;
        lutS[e] = v;
    }
    COMPUTE_K(0, 0);
    LGKM0(); BARR();
    STAGE_K(2, 0);
    WAITVM(2); LGKM0(); BARR();
    COMPUTE_K(1, 1);
    LGKM0(); BARR();
    STAGE_K(3, 1);
    WAITVM(2); LGKM0(); BARR();
    COMPUTE_K(2, 0);
    LGKM0(); BARR();
    STAGE_V(0, 0);
    WAITVM(2); LGKM0(); BARR();
    COMPUTE_K(3, 1);
    LGKM0(); BARR();
    STAGE_V(1, 1);

    // ---- pass A: rel + mask + weights write + per-wave-group (max,sum) ----
#pragma unroll
    for (int i = 0; i < 2; ++i)
#pragma unroll
        for (int r = 0; r < 4; ++r) {
            const int row = i * 16 + quad * 4 + r;
            const int gq = q0 + row;
            const float* lrow = &lutS[row * 32];
            const unsigned short* prow = Pk + (size_t)(b * LQ + gq) * LK;
            float* wrow = weights + ((size_t)z * LQ + gq) * LK;
            float pm = -__builtin_inff();
#pragma unroll
            for (int c = 0; c < 4; ++c) {
                const int col = c * 128 + wave * 16 + l16;
                const unsigned w_ = prow[col];
                const float rel = lrow[w_ & 15u] + lrow[16 + ((w_ >> 4) & 15u)];
                const float wv = (acc[c][i][r] + rel) * 0.125f;
                wrow[col] = wv;
                const float m = ((w_ & 0x1FFu) == 0x100u) ? -__builtin_inff() : wv;
                acc[c][i][r] = m;
                pm = fmaxf(pm, m);
            }
#pragma unroll
            for (int o = 1; o < 16; o <<= 1) pm = fmaxf(pm, __shfl_xor(pm, o, 64));
            float ps = 0.f;
#pragma unroll
            for (int c = 0; c < 4; ++c) {
                const float e = __expf(acc[c][i][r] - pm);
                acc[c][i][r] = e;
                ps += e;
            }
#pragma unroll
            for (int o = 1; o < 16; o <<= 1) ps += __shfl_xor(ps, o, 64);
            if (l16 == 0) { redA[row * 8 + wave] = pm; redB[row * 8 + wave] = ps; }
        }
    LGKM0(); BARR();

    // ---- pass B: merge across 8 wave-groups, normalize, write Ps (f16) ----
#pragma unroll
    for (int i = 0; i < 2; ++i)
#pragma unroll
        for (int r = 0; r < 4; ++r) {
            const int row = i * 16 + quad * 4 + r;
            const f32x4 pa = *(const f32x4*)&redA[row * 8];
            const f32x4 pb = *(const f32x4*)&redA[row * 8 + 4];
            const f32x4 sa = *(const f32x4*)&redB[row * 8];
            const f32x4 sb = *(const f32x4*)&redB[row * 8 + 4];
            const float M = fmaxf(fmaxf(fmaxf(pa[0], pa[1]), fmaxf(pa[2], pa[3])),
                                  fmaxf(fmaxf(pb[0], pb[1]), fmaxf(pb[2], pb[3])));
            const float S = sa[0] * __expf(pa[0] - M) + sa[1] * __expf(pa[1] - M)
                          + sa[2] * __expf(pa[2] - M) + sa[3] * __expf(pa[3] - M)
                          + sb[0] * __expf(pb[0] - M) + sb[1] * __expf(pb[1] - M)
                          + sb[2] * __expf(pb[2] - M) + sb[3] * __expf(pb[3] - M);
            const float own = redA[row * 8 + wave];
            const float alpha = __expf(own - M) / S;
#pragma unroll
            for (int c = 0; c < 4; ++c) {
                const int col = c * 128 + wave * 16 + l16;
                Ps[row * PSTR + col] = (short)f2h(acc[c][i][r] * alpha);
            }
        }
    LGKM0(); BARR();

    // ---- t[q][l] = sum_k attn * em_bit_l, packed-f16 mask FMA ----
    {
        const int row = tid >> 4, l = (tid >> 1) & 7, half = tid & 1;
        const uint4* pw = (const uint4*)(Pk + (size_t)(b * LQ + q0 + row) * LK + half * 256);
        const uint4* aw = (const uint4*)&Ps[row * PSTR + half * 256];
        float tv = 0.f;
#pragma unroll 4
        for (int kk = 0; kk < 32; ++kk) {
            const uint4 wb = pw[kk];
            const uint4 av = aw[kk];
            const unsigned w4[4] = {wb.x, wb.y, wb.z, wb.w};
            const unsigned a4[4] = {av.x, av.y, av.z, av.w};
            f16x2 hacc = {(_Float16)0.f, (_Float16)0.f};
#pragma unroll
            for (int u = 0; u < 4; ++u) {
                const unsigned bits = (w4[u] >> l) & 0x10001u;
                const unsigned msk = bits * 0x3c00u;
                hacc += __builtin_bit_cast(f16x2, a4[u]) * __builtin_bit_cast(f16x2, msk);
            }
            tv += (float)hacc[0] + (float)hacc[1];
        }
        tv += __shfl_xor(tv, 1, 64);
        if (half == 0) tS[row * 8 + l] = tv;
    }

    // ================= V pipeline =================
    f32x4 oacc = zz;
    const int mi = wave & 1, ni = wave >> 1;
    WAITVM(0); LGKM0(); BARR();
    COMPUTE_V(0, 0);
    BARR();
    STAGE_V(2, 0);
    WAITVM(2); LGKM0(); BARR();
    COMPUTE_V(1, 1);
    BARR();
    STAGE_V(3, 1);
    WAITVM(2); LGKM0(); BARR();
    COMPUTE_V(2, 0);
    WAITVM(0); LGKM0(); BARR();
    COMPUTE_V(3, 1);

    // ---- output epilogue: + qvr, store Hb bf16 ----
    const int gd = ni * 16 + l16;
    float bvv[NL];
#pragma unroll
    for (int l = 0; l < NL; ++l) bvv[l] = b_vs[l * DQ + gd];
#pragma unroll
    for (int r = 0; r < 4; ++r) {
        const int row = mi * 16 + quad * 4 + r;
        const float* tp = &tS[row * 8];
        float o = oacc[r];
#pragma unroll
        for (int l = 0; l < NL; ++l) o = fmaf(tp[l], bvv[l], o);
        Hb[(size_t)(b * LQ + q0 + row) * DM + h * DQ + gd] = f2bf(o);
    }
}

// ===========================================================================
// Cooperative mega-kernel: all 4 phases in ONE dispatch, grid.sync between.
// Grid 512 x 512thr; LDS 78336 B -> exactly 2 blocks/CU; (512,4) caps VGPR
// at 128 so the cooperative occupancy check admits all 512 blocks.
// ===========================================================================
__global__ __launch_bounds__(512, 4) void mega(
        const float* __restrict__ q,  const float* __restrict__ k,
        const float* __restrict__ em, const float* __restrict__ pad,
        const float* __restrict__ w_q_w, const float* __restrict__ w_q_b,
        const float* __restrict__ w_k,   const float* __restrict__ w_v,
        const float* __restrict__ w_h_w, const float* __restrict__ w_h_b,
        const float* __restrict__ b_ks,  const float* __restrict__ b_vs,
        unsigned short* __restrict__ qb,  unsigned short* __restrict__ kb,
        unsigned short* __restrict__ wqb, unsigned short* __restrict__ wkb,
        unsigned short* __restrict__ wvb, unsigned short* __restrict__ whb,
        unsigned short* __restrict__ Qp,  unsigned short* __restrict__ Kp,
        unsigned short* __restrict__ Vt,  unsigned short* __restrict__ Hb,
        unsigned short* __restrict__ Pk,
        float* __restrict__ weights, float* __restrict__ out) {
    __shared__ __align__(16) char smemc[SM_TOTAL];
    cg::grid_group grid = cg::this_grid();
    const int bid = blockIdx.x, tid = threadIdx.x;

    // ---- phase 0: conversions (393216 vec8 units) + Pk pack ----
    {
        for (int u = bid * 512 + tid; u < 393216; u += 262144) {
            const float* s; unsigned short* d; int idx;
            if (u < 131072)      { s = q; d = qb; idx = u; }
            else if (u < 262144) { s = k; d = kb; idx = u - 131072; }
            else {
                const int v = u - 262144, w = v >> 15; idx = v & 32767;
                switch (w) {
                    case 0: s = w_q_w; d = wqb; break;
                    case 1: s = w_k;   d = wkb; break;
                    case 2: s = w_v;   d = wvb; break;
                    default: s = w_h_w; d = whb; break;
                }
            }
            conv_vec8(s, d, idx);
        }
        const int u2 = bid * 512 + tid;              // 131072 lane-tasks
        if (u2 < 131072) pack_pk(em, pad, Pk, u2 >> 6, (u2 & 63) * 8);
    }
    grid.sync();

    // ---- phase 1: input projections, 384 macro-tiles of 64x128 ----
    if (bid < 384) {
        const int mat = bid >> 7, t = bid & 127;
        const int m0 = (t >> 2) * 64, n0p = (t & 3) * 128;
        if (mat == 0)      gemm_macro<0>(qb, wqb, w_q_b,  Qp, m0, n0p, smemc);
        else if (mat == 1) gemm_macro<0>(kb, wkb, nullptr, Kp, m0, n0p, smemc);
        else               gemm_macro<1>(kb, wvb, nullptr, Vt, m0, n0p, smemc);
    }
    grid.sync();

    // ---- phase 2: fused attention, one (tile, z) unit per block ----
    attn_body(smemc, bid & 15, bid >> 4, Qp, Kp, Vt, Pk, b_ks, b_vs, weights, Hb);
    grid.sync();

    // ---- phase 3: output projection, 128 macro-tiles of 64x128 ----
    if (bid < 128) {
        const int m0 = (bid >> 2) * 64, n0p = (bid & 3) * 128;
        gemm_macro<2>(Hb, whb, w_h_b, out, m0, n0p, smemc);
    }
}

// ===========================================================================
// Fallback path: the verified round-3 four-kernel pipeline (used only if the
// cooperative launch is rejected, e.g. by graph capture).
// ===========================================================================
__global__ __launch_bounds__(256) void prep_kernel(
        const float* __restrict__ q,  const float* __restrict__ k,
        const float* __restrict__ wq, const float* __restrict__ wk,
        const float* __restrict__ wv, const float* __restrict__ wh,
        const float* __restrict__ em, const float* __restrict__ pad,
        unsigned short* __restrict__ qb,  unsigned short* __restrict__ kb,
        unsigned short* __restrict__ wqb, unsigned short* __restrict__ wkb,
        unsigned short* __restrict__ wvb, unsigned short* __restrict__ whb,
        unsigned short* __restrict__ Pk) {
    const int tid = threadIdx.x;
    const int y = blockIdx.y;
    if (y < 6) {
        const float* s; unsigned short* d; int n;
        switch (y) {
            case 0: s = q;  d = qb;  n = NB * LQ * DM; break;
            case 1: s = k;  d = kb;  n = NB * LK * DM; break;
            case 2: s = wq; d = wqb; n = DM * DM; break;
            case 3: s = wk; d = wkb; n = DM * DM; break;
            case 4: s = wv; d = wvb; n = DM * DM; break;
            default: s = wh; d = whb; n = DM * DM; break;
        }
        const int i = blockIdx.x * 256 + tid;
        if (i * 8 >= n) return;
        conv_vec8(s, d, i);
    } else {
        const int row = blockIdx.x * 4 + (tid >> 6);
        pack_pk(em, pad, Pk, row, (tid & 63) * 8);
    }
}

__device__ __forceinline__ void gemm64core(const unsigned short* __restrict__ Ag, int lda,
                                           const unsigned short* __restrict__ Bg, int ldb,
                                           short* As, short* Bs,
                                           f32x4 (&acc)[2][2]) {
    const int tid = threadIdx.x;
    const int wave = tid >> 6, lane = tid & 63;
    const int quad = lane >> 4, l16 = lane & 15;
    const int wr = wave >> 1, wc = wave & 1;
    const int r_ = tid >> 2, c_ = (tid & 3) * 8;
    const unsigned short* Ar = Ag + (size_t)r_ * lda + c_;
    const unsigned short* Br = Bg + (size_t)r_ * ldb + c_;
    gld16(Ar, (char*)As + wave * 1024);
    gld16(Br, (char*)Bs + wave * 1024);
#pragma unroll
    for (int s = 0; s < 16; ++s) {
        if (s < 15) {
            const int nb = (s + 1) & 1;
            gld16(Ar + (s + 1) * 32, (char*)As + nb * 4096 + wave * 1024);
            gld16(Br + (s + 1) * 32, (char*)Bs + nb * 4096 + wave * 1024);
            WAITVM(2);
        } else {
            WAITVM(0);
        }
        BARR();
        const int cb = s & 1;
        bf16x8 af[2], bf[2];
#pragma unroll
        for (int i = 0; i < 2; ++i)
            af[i] = *(const bf16x8*)&As[cb * 2048 + (wr * 32 + i * 16 + l16) * 32 + quad * 8];
#pragma unroll
        for (int j = 0; j < 2; ++j)
            bf[j] = *(const bf16x8*)&Bs[cb * 2048 + (wc * 32 + j * 16 + l16) * 32 + quad * 8];
#pragma unroll
        for (int i = 0; i < 2; ++i)
#pragma unroll
            for (int j = 0; j < 2; ++j)
                acc[i][j] = __builtin_amdgcn_mfma_f32_16x16x32_bf16(af[i], bf[j], acc[i][j], 0, 0, 0);
        BARR();
    }
}

__global__ __launch_bounds__(256) void proj_all(const unsigned short* __restrict__ qb,
                                                const unsigned short* __restrict__ kb,
                                                const unsigned short* __restrict__ wqb,
                                                const unsigned short* __restrict__ wkb,
                                                const unsigned short* __restrict__ wvb,
                                                const float* __restrict__ w_q_b,
                                                unsigned short* __restrict__ Qp,
                                                unsigned short* __restrict__ Kp,
                                                unsigned short* __restrict__ Vt) {
    __shared__ __align__(16) short As[2][64 * 32];
    __shared__ __align__(16) short Bs[2][64 * 32];
    const unsigned short* A; const unsigned short* W; const float* bias;
    unsigned short* C; int mode;
    switch (blockIdx.z) {
        case 0:  A = qb; W = wqb; bias = w_q_b;  C = Qp; mode = 0; break;
        case 1:  A = kb; W = wkb; bias = nullptr; C = Kp; mode = 0; break;
        default: A = kb; W = wvb; bias = nullptr; C = Vt; mode = 1; break;
    }
    f32x4 acc[2][2];
    const f32x4 zz = {0.f, 0.f, 0.f, 0.f};
#pragma unroll
    for (int i = 0; i < 2; ++i)
#pragma unroll
        for (int j = 0; j < 2; ++j) acc[i][j] = zz;
    const int m0 = blockIdx.x * 64, n0 = blockIdx.y * 64;
    gemm64core(A + (size_t)m0 * DM, DM, W + (size_t)n0 * DM, DM, &As[0][0], &Bs[0][0], acc);
    const int tid = threadIdx.x, wave = tid >> 6, lane = tid & 63;
    const int quad = lane >> 4, l16 = lane & 15;
    const int wr = wave >> 1, wc = wave & 1;
#pragma unroll
    for (int i = 0; i < 2; ++i)
#pragma unroll
        for (int r = 0; r < 4; ++r) {
            const int gm = m0 + wr * 32 + i * 16 + quad * 4 + r;
#pragma unroll
            for (int j = 0; j < 2; ++j) {
                const int gn = n0 + wc * 32 + j * 16 + l16;
                float v = acc[i][j][r];
                if (bias) v += bias[gn];
                if (mode == 0) C[(size_t)gm * DM + gn] = f2bf(v);
                else C[(size_t)(gm >> 9) * (DM * LK) + (size_t)gn * LK + (gm & 511)] = f2h(v);
            }
        }
}

__global__ __launch_bounds__(512, 4) void attn_fused(
        const unsigned short* __restrict__ Qp,
        const unsigned short* __restrict__ Kp,
        const unsigned short* __restrict__ Vt,
        const unsigned short* __restrict__ Pk,
        const float* __restrict__ b_ks,
        const float* __restrict__ b_vs,
        float* __restrict__ weights,
        unsigned short* __restrict__ Hb) {
    __shared__ __align__(16) char smemc[SM_TOTAL];
    attn_body(smemc, blockIdx.x, blockIdx.y, Qp, Kp, Vt, Pk, b_ks, b_vs, weights, Hb);
}

__global__ __launch_bounds__(256) void outproj_mfma(const unsigned short* __restrict__ Hb,
                                                    const unsigned short* __restrict__ whb,
                                                    const float* __restrict__ bias,
                                                    float* __restrict__ C) {
    __shared__ __align__(16) short As[2][64 * 32];
    __shared__ __align__(16) short Bs[2][64 * 32];
    f32x4 acc[2][2];
    const f32x4 zz = {0.f, 0.f, 0.f, 0.f};
#pragma unroll
    for (int i = 0; i < 2; ++i)
#pragma unroll
        for (int j = 0; j < 2; ++j) acc[i][j] = zz;
    const int m0 = blockIdx.x * 64, n0 = blockIdx.y * 64;
    gemm64core(Hb + (size_t)m0 * DM, DM, whb + (size_t)n0 * DM, DM, &As[0][0], &Bs[0][0], acc);
    const int tid = threadIdx.x, wave = tid >> 6, lane = tid & 63;
    const int quad = lane >> 4, l16 = lane & 15;
    const int wr = wave >> 1, wc = wave & 1;
#pragma unroll
    for (int i = 0; i < 2; ++i)
#pragma unroll
        for (int r = 0; r < 4; ++r) {
            const int gm = m0 + wr * 32 + i * 16 + quad * 4 + r;
#pragma unroll
            for (int j = 0; j < 2; ++j) {
                const int gn = n0 + wc * 32 + j * 16 + l16;
                C[(size_t)gm * DM + gn] = acc[i][j][r] + bias[gn];
            }
        }
}

// ---------------------------------------------------------------------------
extern "C" void kernel_launch(void* const* d_in, const int* in_sizes, int n_in,
                              void* d_out, int out_size, void* d_ws, size_t ws_size,
                              hipStream_t stream) {
    const float* q     = (const float*)d_in[0];
    const float* k     = (const float*)d_in[1];
    const float* em    = (const float*)d_in[2];
    const float* pad   = (const float*)d_in[3];
    const float* w_q_w = (const float*)d_in[4];
    const float* w_q_b = (const float*)d_in[5];
    const float* w_k   = (const float*)d_in[6];
    const float* w_v   = (const float*)d_in[7];
    const float* w_h_w = (const float*)d_in[8];
    const float* w_h_b = (const float*)d_in[9];
    const float* b_ks  = (const float*)d_in[10];
    const float* b_vs  = (const float*)d_in[11];

    float* out     = (float*)d_out;                       // (B, LQ, DM) fp32
    float* weights = out + (size_t)NB * LQ * DM;          // (H*B, LQ, LK) fp32

    char* ws = (char*)d_ws;
    unsigned short* qb  = (unsigned short*)(ws + 0);          // 2 MB
    unsigned short* kb  = (unsigned short*)(ws + 2097152);    // 2 MB
    unsigned short* wqb = (unsigned short*)(ws + 4194304);    // 512 KB
    unsigned short* wkb = (unsigned short*)(ws + 4718592);
    unsigned short* wvb = (unsigned short*)(ws + 5242880);
    unsigned short* whb = (unsigned short*)(ws + 5767168);
    unsigned short* Qp  = (unsigned short*)(ws + 6291456);    // 2 MB bf16
    unsigned short* Kp  = (unsigned short*)(ws + 8388608);    // 2 MB bf16
    unsigned short* Vt  = (unsigned short*)(ws + 10485760);   // 2 MB f16 [b][d][k]
    unsigned short* Hb  = (unsigned short*)(ws + 12582912);   // 2 MB bf16
    unsigned short* Pk  = (unsigned short*)(ws + 14680064);   // 2 MB 9-bit packs

    void* args[] = { (void*)&q, (void*)&k, (void*)&em, (void*)&pad,
                     (void*)&w_q_w, (void*)&w_q_b, (void*)&w_k, (void*)&w_v,
                     (void*)&w_h_w, (void*)&w_h_b, (void*)&b_ks, (void*)&b_vs,
                     (void*)&qb, (void*)&kb, (void*)&wqb, (void*)&wkb,
                     (void*)&wvb, (void*)&whb, (void*)&Qp, (void*)&Kp,
                     (void*)&Vt, (void*)&Hb, (void*)&Pk,
                     (void*)&weights, (void*)&out };
    hipError_t e = hipLaunchCooperativeKernel(reinterpret_cast<void*>(mega),
                                              dim3(512), dim3(512), args, 0, stream);
    if (e != hipSuccess) {
        (void)hipGetLastError();   // clear sticky error, fall back to 4-kernel path
        prep_kernel<<<dim3(512, 7), 256, 0, stream>>>(q, k, w_q_w, w_k, w_v, w_h_w,
                                                      em, pad, qb, kb, wqb, wkb, wvb, whb, Pk);
        proj_all<<<dim3(32, 8, 3), 256, 0, stream>>>(qb, kb, wqb, wkb, wvb, w_q_b, Qp, Kp, Vt);
        attn_fused<<<dim3(LQ / QT, 32), 512, 0, stream>>>(Qp, Kp, Vt, Pk, b_ks, b_vs, weights, Hb);
        outproj_mfma<<<dim3(32, 8), 256, 0, stream>>>(Hb, whb, w_h_b, out);
    }
}

// Round 5
// 164.141 us; speedup vs baseline: 2.2770x; 2.2770x over previous
//
#include <hip/hip_runtime.h>
#include <math.h>

#define NB 4
#define LQ 512
#define LK 512
#define DM 512
#define NH 8
#define DQ 64
#define NL 8
#define QT 32          // q-rows per attn block
#define PSTR 520       // Ps row stride in shorts (260 dwords % 32 = 4 -> 2-way max)

typedef short bf16x8 __attribute__((ext_vector_type(8)));
typedef _Float16 f16x8 __attribute__((ext_vector_type(8)));
typedef _Float16 f16x2 __attribute__((ext_vector_type(2)));
typedef float f32x4 __attribute__((ext_vector_type(4)));
typedef unsigned u32x4 __attribute__((ext_vector_type(4)));

__device__ __forceinline__ unsigned short f2bf(float x) {
    unsigned u = __float_as_uint(x);
    u += 0x7fff + ((u >> 16) & 1);          // RNE
    return (unsigned short)(u >> 16);
}
__device__ __forceinline__ float bf2f(unsigned x) {
    return __uint_as_float(x << 16);
}
__device__ __forceinline__ unsigned short f2h(float x) {
    _Float16 h = (_Float16)x;               // v_cvt_f16_f32 (RNE)
    return __builtin_bit_cast(unsigned short, h);
}
// async global->LDS, 16B/lane; LDS dest = wave-uniform base + lane*16
__device__ __forceinline__ void gld16(const void* g, void* l) {
    __builtin_amdgcn_global_load_lds(
        (const __attribute__((address_space(1))) void*)g,
        (__attribute__((address_space(3))) void*)l, 16, 0, 0);
}

#define WAITVM(N) asm volatile("s_waitcnt vmcnt(" #N ")" ::: "memory")
#define LGKM0()   asm volatile("s_waitcnt lgkmcnt(0)" ::: "memory")
#define BARR()    do { asm volatile("" ::: "memory"); \
                       __builtin_amdgcn_s_barrier();  \
                       asm volatile("" ::: "memory"); } while (0)

// pack 8 fp32 -> bf16x8 via v_cvt_pk_bf16_f32 (RNE, identical to f2bf)
__device__ __forceinline__ bf16x8 pk_bf16x8(f32x4 a, f32x4 b) {
    unsigned r0, r1, r2, r3;
    asm("v_cvt_pk_bf16_f32 %0, %1, %2" : "=v"(r0) : "v"(a[0]), "v"(a[1]));
    asm("v_cvt_pk_bf16_f32 %0, %1, %2" : "=v"(r1) : "v"(a[2]), "v"(a[3]));
    asm("v_cvt_pk_bf16_f32 %0, %1, %2" : "=v"(r2) : "v"(b[0]), "v"(b[1]));
    asm("v_cvt_pk_bf16_f32 %0, %1, %2" : "=v"(r3) : "v"(b[2]), "v"(b[3]));
    const u32x4 u = {r0, r1, r2, r3};
    return __builtin_bit_cast(bf16x8, u);
}

// fp32 64x32 tile staging: forced-linear LDS => pre-swizzle the SOURCE chunk
// (slot sl holds global chunk sl^(row&7)); the fragment read applies the same
// XOR.  2-way max bank conflict on the f32x4 reads (slot spreads 8 bank-quads
// over each 8-row stripe; rows r and r+8 alias -> free).
#define STG_FF(Mg, base, k0) do {                                          \
    _Pragma("unroll")                                                      \
    for (int it_ = 0; it_ < 2; ++it_) {                                    \
        const int t_ = it_ * 256 + tid;                                    \
        const int row_ = t_ >> 3, sl_ = t_ & 7;                            \
        const int gch_ = sl_ ^ (row_ & 7);                                 \
        gld16((Mg) + (size_t)row_ * DM + (k0) + gch_ * 4,                  \
              (char*)(base) + it_ * 4096 + wave * 1024);                   \
    } } while (0)

__device__ __forceinline__ bf16x8 ldfrag_f32(const float* Mf, int row, int quad) {
    const int s0 = (2 * quad) ^ (row & 7), s1 = (2 * quad + 1) ^ (row & 7);
    const f32x4 lo = *(const f32x4*)&Mf[row * 32 + s0 * 4];
    const f32x4 hi = *(const f32x4*)&Mf[row * 32 + s1 * 4];
    return pk_bf16x8(lo, hi);
}

// ---- em/pad 9-bit pack (verbatim from the verified pipeline) --------------
__device__ __forceinline__ void pack_pk(const float* __restrict__ em,
                                        const float* __restrict__ pad,
                                        unsigned short* __restrict__ Pk,
                                        int row, int k0) {
    const float* eb = em + ((size_t)row * LK + k0) * NL;
    const float4 pv0 = *(const float4*)(pad + (size_t)row * LK + k0);
    const float4 pv1 = *(const float4*)(pad + (size_t)row * LK + k0 + 4);
    const float pv[8] = {pv0.x, pv0.y, pv0.z, pv0.w, pv1.x, pv1.y, pv1.z, pv1.w};
    unsigned short outv[8];
#pragma unroll
    for (int kk = 0; kk < 8; ++kk) {
        const float4 v0 = *(const float4*)(eb + kk * 8);
        const float4 v1 = *(const float4*)(eb + kk * 8 + 4);
        unsigned b_ = 0;
        b_ |= (v0.x != 0.f) << 0; b_ |= (v0.y != 0.f) << 1;
        b_ |= (v0.z != 0.f) << 2; b_ |= (v0.w != 0.f) << 3;
        b_ |= (v1.x != 0.f) << 4; b_ |= (v1.y != 0.f) << 5;
        b_ |= (v1.z != 0.f) << 6; b_ |= (v1.w != 0.f) << 7;
        b_ |= (pv[kk] != 0.f) << 8;
        outv[kk] = (unsigned short)b_;
    }
    uint4 o;
    o.x = (unsigned)outv[0] | ((unsigned)outv[1] << 16);
    o.y = (unsigned)outv[2] | ((unsigned)outv[3] << 16);
    o.z = (unsigned)outv[4] | ((unsigned)outv[5] << 16);
    o.w = (unsigned)outv[6] | ((unsigned)outv[7] << 16);
    *(uint4*)(Pk + (size_t)row * LK + k0) = o;
}

// ---------------------------------------------------------------------------
// fp32-input MFMA GEMM core: C(64x64) = A(64x512) * B(64x512)^T, BK=32,
// double-buffered counted-vmcnt (4 gld16/wave/step -> WAITVM(4)).  Inputs are
// the ORIGINAL fp32 tensors; bf16 conversion happens at fragment read (RNE,
// bit-identical to the old prep path).  MODE: 0 = bf16 C (+opt bias),
// 1 = Vt f16 transposed.
// ---------------------------------------------------------------------------
template<int MODE>
__device__ void gemm_ff(const float* __restrict__ Ag,
                        const float* __restrict__ Bg,
                        const float* __restrict__ bias,
                        unsigned short* __restrict__ Cp,
                        int m0, int n0, float* As, float* Bs) {
    const int tid = threadIdx.x;
    const int wave = tid >> 6, lane = tid & 63;
    const int quad = lane >> 4, l16 = lane & 15;
    const int wr = wave >> 1, wc = wave & 1;
    f32x4 acc[2][2];
    const f32x4 zz = {0.f, 0.f, 0.f, 0.f};
#pragma unroll
    for (int i = 0; i < 2; ++i)
#pragma unroll
        for (int j = 0; j < 2; ++j) acc[i][j] = zz;
    STG_FF(Ag, (char*)As, 0);
    STG_FF(Bg, (char*)Bs, 0);
#pragma unroll
    for (int s = 0; s < 16; ++s) {
        if (s < 15) {
            const int nb = (s + 1) & 1;
            STG_FF(Ag, (char*)As + nb * 8192, (s + 1) * 32);
            STG_FF(Bg, (char*)Bs + nb * 8192, (s + 1) * 32);
            WAITVM(4);                  // current step landed; next in flight
        } else {
            WAITVM(0);
        }
        BARR();
        const int cb = s & 1;
        const float* Af = As + cb * 2048;
        const float* Bf = Bs + cb * 2048;
        bf16x8 af[2], bf[2];
#pragma unroll
        for (int i = 0; i < 2; ++i)
            af[i] = ldfrag_f32(Af, wr * 32 + i * 16 + l16, quad);
#pragma unroll
        for (int j = 0; j < 2; ++j)
            bf[j] = ldfrag_f32(Bf, wc * 32 + j * 16 + l16, quad);
#pragma unroll
        for (int i = 0; i < 2; ++i)
#pragma unroll
            for (int j = 0; j < 2; ++j)
                acc[i][j] = __builtin_amdgcn_mfma_f32_16x16x32_bf16(af[i], bf[j], acc[i][j], 0, 0, 0);
        BARR();
    }
#pragma unroll
    for (int i = 0; i < 2; ++i)
#pragma unroll
        for (int r = 0; r < 4; ++r) {
            const int gm = m0 + wr * 32 + i * 16 + quad * 4 + r;
#pragma unroll
            for (int j = 0; j < 2; ++j) {
                const int gn = n0 + wc * 32 + j * 16 + l16;
                float v = acc[i][j][r];
                if (MODE == 0) {
                    if (bias) v += bias[gn];
                    Cp[(size_t)gm * DM + gn] = f2bf(v);
                } else {
                    Cp[(size_t)(gm >> 9) * (DM * LK) + (size_t)gn * LK + (gm & 511)] = f2h(v);
                }
            }
        }
}

// ---------------------------------------------------------------------------
// front: grid (32, 8, 4).  z<3: Q/K/V projections straight from fp32 inputs.
// z==3: em/pad -> Pk 9-bit pack (the old prep y=6), folded in to kill the
// prep dispatch.
// ---------------------------------------------------------------------------
__global__ __launch_bounds__(256) void front(
        const float* __restrict__ q,  const float* __restrict__ k,
        const float* __restrict__ wq, const float* __restrict__ wk,
        const float* __restrict__ wv, const float* __restrict__ w_q_b,
        const float* __restrict__ em, const float* __restrict__ pad,
        unsigned short* __restrict__ Qp, unsigned short* __restrict__ Kp,
        unsigned short* __restrict__ Vt, unsigned short* __restrict__ Pk) {
    const int tid = threadIdx.x;
    if (blockIdx.z == 3) {
        const int blk = blockIdx.y * 32 + blockIdx.x;    // 0..255
#pragma unroll
        for (int p = 0; p < 2; ++p) {
            const int row = blk * 8 + p * 4 + (tid >> 6);
            pack_pk(em, pad, Pk, row, (tid & 63) * 8);
        }
        return;
    }
    __shared__ __align__(16) float As[2][2048];   // 16 KB
    __shared__ __align__(16) float Bs[2][2048];   // 16 KB
    const int m0 = blockIdx.x * 64, n0 = blockIdx.y * 64;
    if (blockIdx.z == 0)
        gemm_ff<0>(q + (size_t)m0 * DM, wq + (size_t)n0 * DM, w_q_b, Qp, m0, n0,
                   &As[0][0], &Bs[0][0]);
    else if (blockIdx.z == 1)
        gemm_ff<0>(k + (size_t)m0 * DM, wk + (size_t)n0 * DM, nullptr, Kp, m0, n0,
                   &As[0][0], &Bs[0][0]);
    else
        gemm_ff<1>(k + (size_t)m0 * DM, wv + (size_t)n0 * DM, nullptr, Vt, m0, n0,
                   &As[0][0], &Bs[0][0]);
}

// ---------------------------------------------------------------------------
// Fused attention (VERBATIM round-3 body: 8-slot counted-vmcnt pipeline).
// ---------------------------------------------------------------------------
#define STAGE_K(c, hb) do {                                                       \
    _Pragma("unroll")                                                             \
    for (int it_ = 0; it_ < 2; ++it_) {                                           \
        const int e_ = it_ * 512 + tid;                                           \
        const int kr_ = e_ >> 3, ch_ = e_ & 7;                                    \
        gld16(Kp + (size_t)(b * LK + (c) * 128 + kr_) * DM + h * DQ               \
                  + ((ch_ ^ (kr_ & 7)) * 8),                                      \
              (char*)(&Kc[hb][0]) + it_ * 8192 + wave * 1024);                    \
    } } while (0)

#define STAGE_V(vc, hb) do {                                                      \
    _Pragma("unroll")                                                             \
    for (int it_ = 0; it_ < 2; ++it_) {                                           \
        const int e_ = it_ * 512 + tid;                                           \
        const int dd_ = e_ >> 4, ch_ = e_ & 15;                                   \
        gld16(Vt + (size_t)(b * DM + h * DQ + dd_) * LK + (vc) * 128              \
                  + ((ch_ ^ (dd_ & 15)) * 8),                                     \
              (char*)(&Kc[hb][0]) + it_ * 8192 + wave * 1024);                    \
    } } while (0)

#define COMPUTE_K(c, hb) do {                                                     \
    _Pragma("unroll")                                                             \
    for (int kdi_ = 0; kdi_ < 2; ++kdi_) {                                        \
        const int krow_ = wave * 16 + l16;                                        \
        const int kch_ = (kdi_ * 4 + quad) ^ (krow_ & 7);                         \
        const bf16x8 bfv_ = *(const bf16x8*)&Kc[hb][krow_ * 64 + kch_ * 8];       \
        acc[c][0] = __builtin_amdgcn_mfma_f32_16x16x32_bf16(qf[0][kdi_], bfv_,    \
                                                            acc[c][0], 0, 0, 0); \
        acc[c][1] = __builtin_amdgcn_mfma_f32_16x16x32_bf16(qf[1][kdi_], bfv_,    \
                                                            acc[c][1], 0, 0, 0); \
    } } while (0)

#define COMPUTE_V(vc, hb) do {                                                    \
    _Pragma("unroll")                                                             \
    for (int kd_ = 0; kd_ < 128; kd_ += 32) {                                     \
        const int vrow_ = ni * 16 + l16;                                          \
        const int vch_ = ((kd_ >> 3) + quad) ^ (vrow_ & 15);                      \
        const f16x8 afv_ = *(const f16x8*)&Ps[(mi * 16 + l16) * PSTR              \
                                              + (vc) * 128 + kd_ + quad * 8];     \
        const f16x8 bfv_ = *(const f16x8*)&Kc[hb][vrow_ * 128 + vch_ * 8];        \
        oacc = __builtin_amdgcn_mfma_f32_16x16x32_f16(afv_, bfv_, oacc, 0, 0, 0); \
    } } while (0)

__global__ __launch_bounds__(512, 4) void attn_fused(
        const unsigned short* __restrict__ Qp,
        const unsigned short* __restrict__ Kp,
        const unsigned short* __restrict__ Vt,     // f16 [b][d][k]
        const unsigned short* __restrict__ Pk,
        const float* __restrict__ b_ks,
        const float* __restrict__ b_vs,
        float* __restrict__ weights,
        unsigned short* __restrict__ Hb) {
    __shared__ __align__(16) short Qs[QT * 64];       // 4 KB   [q][d] swizzled
    __shared__ __align__(16) short Kc[2][128 * 64];   // 32 KB  K/V double buffer
    __shared__ __align__(16) short Ps[QT * PSTR];     // 32.5 KB attn f16
    __shared__ float svS[QT * NL];
    __shared__ float lutS[QT * 32];                   // nibble LUT [row][lo16|hi16]
    __shared__ float tS[QT * NL];
    __shared__ float redA[QT * 8];                    // per-wave-group max
    __shared__ float redB[QT * 8];                    // per-wave-group sum

    const int tid = threadIdx.x, wave = tid >> 6, lane = tid & 63;
    const int quad = lane >> 4, l16 = lane & 15;
    const int q0 = blockIdx.x * QT;
    const int z = blockIdx.y, h = z >> 2, b = z & 3;

    // ---- svS source loads (issued before the stages in program order) ----
    const int srow = tid >> 4, sl = (tid >> 1) & 7, shalf = tid & 1;
    bf16x8 sq[4];
    {
        const unsigned short* qrow = Qp + (size_t)(b * LQ + q0 + srow) * DM + h * DQ + shalf * 32;
#pragma unroll
        for (int d0 = 0; d0 < 4; ++d0) sq[d0] = *(const bf16x8*)&qrow[d0 * 8];
    }

    // ---- stage Q tile (swizzled) + K0/K1 double-buffer prologue ----
    if (tid < 256) {
        const int row = tid >> 3, ch = tid & 7;
        gld16(Qp + (size_t)(b * LQ + q0 + row) * DM + h * DQ + ((ch ^ (row & 7)) * 8),
              (char*)Qs + wave * 1024);
    }
    STAGE_K(0, 0);
    STAGE_K(1, 1);

    // ---- svS[row][l] = sum_d Q[row][d] * b_ks[l][d] (register data) ----
    {
        const float* bk = b_ks + sl * DQ + shalf * 32;
        float s = 0.f;
#pragma unroll
        for (int d0 = 0; d0 < 4; ++d0)
#pragma unroll
            for (int j = 0; j < 8; ++j)
                s = fmaf(bf2f((unsigned short)sq[d0][j]), bk[d0 * 8 + j], s);
        s += __shfl_xor(s, 1, 64);
        if (shalf == 0) svS[srow * 8 + sl] = s;
    }

    f32x4 acc[4][2];
    const f32x4 zz = {0.f, 0.f, 0.f, 0.f};
#pragma unroll
    for (int c = 0; c < 4; ++c) { acc[c][0] = zz; acc[c][1] = zz; }
    bf16x8 qf[2][2];

    // ================= K pipeline =================
    WAITVM(2); LGKM0(); BARR();
#pragma unroll
    for (int i = 0; i < 2; ++i)
#pragma unroll
        for (int kdi = 0; kdi < 2; ++kdi)
            qf[i][kdi] = *(const bf16x8*)&Qs[(i * 16 + l16) * 64
                                             + (((kdi * 4) + quad) ^ (l16 & 7)) * 8];
#pragma unroll
    for (int e2 = 0; e2 < 2; ++e2) {
        const int e = e2 * 512 + tid;
        const int row = e >> 5, idx = e & 31;
        const float* sp = &svS[row * 8 + ((idx & 16) ? 4 : 0)];
        float v = 0.f;
        v += (idx & 1) ? sp[0] : 0.f;
        v += (idx & 2) ? sp[1] : 0.f;
        v += (idx & 4) ? sp[2] : 0.f;
        v += (idx & 8) ? sp[3] : 0.f;
        lutS[e] = v;
    }
    COMPUTE_K(0, 0);
    LGKM0(); BARR();
    STAGE_K(2, 0);
    WAITVM(2); LGKM0(); BARR();
    COMPUTE_K(1, 1);
    LGKM0(); BARR();
    STAGE_K(3, 1);
    WAITVM(2); LGKM0(); BARR();
    COMPUTE_K(2, 0);
    LGKM0(); BARR();
    STAGE_V(0, 0);
    WAITVM(2); LGKM0(); BARR();
    COMPUTE_K(3, 1);
    LGKM0(); BARR();
    STAGE_V(1, 1);

    // ---- pass A: rel + mask + weights write + per-wave-group (max,sum) ----
#pragma unroll
    for (int i = 0; i < 2; ++i)
#pragma unroll
        for (int r = 0; r < 4; ++r) {
            const int row = i * 16 + quad * 4 + r;
            const int gq = q0 + row;
            const float* lrow = &lutS[row * 32];
            const unsigned short* prow = Pk + (size_t)(b * LQ + gq) * LK;
            float* wrow = weights + ((size_t)z * LQ + gq) * LK;
            float pm = -__builtin_inff();
#pragma unroll
            for (int c = 0; c < 4; ++c) {
                const int col = c * 128 + wave * 16 + l16;
                const unsigned w_ = prow[col];
                const float rel = lrow[w_ & 15u] + lrow[16 + ((w_ >> 4) & 15u)];
                const float wv = (acc[c][i][r] + rel) * 0.125f;
                wrow[col] = wv;
                const float m = ((w_ & 0x1FFu) == 0x100u) ? -__builtin_inff() : wv;
                acc[c][i][r] = m;
                pm = fmaxf(pm, m);
            }
#pragma unroll
            for (int o = 1; o < 16; o <<= 1) pm = fmaxf(pm, __shfl_xor(pm, o, 64));
            float ps = 0.f;
#pragma unroll
            for (int c = 0; c < 4; ++c) {
                const float e = __expf(acc[c][i][r] - pm);
                acc[c][i][r] = e;
                ps += e;
            }
#pragma unroll
            for (int o = 1; o < 16; o <<= 1) ps += __shfl_xor(ps, o, 64);
            if (l16 == 0) { redA[row * 8 + wave] = pm; redB[row * 8 + wave] = ps; }
        }
    LGKM0(); BARR();

    // ---- pass B: merge across 8 wave-groups, normalize, write Ps (f16) ----
#pragma unroll
    for (int i = 0; i < 2; ++i)
#pragma unroll
        for (int r = 0; r < 4; ++r) {
            const int row = i * 16 + quad * 4 + r;
            const f32x4 pa = *(const f32x4*)&redA[row * 8];
            const f32x4 pb = *(const f32x4*)&redA[row * 8 + 4];
            const f32x4 sa = *(const f32x4*)&redB[row * 8];
            const f32x4 sb = *(const f32x4*)&redB[row * 8 + 4];
            const float M = fmaxf(fmaxf(fmaxf(pa[0], pa[1]), fmaxf(pa[2], pa[3])),
                                  fmaxf(fmaxf(pb[0], pb[1]), fmaxf(pb[2], pb[3])));
            const float S = sa[0] * __expf(pa[0] - M) + sa[1] * __expf(pa[1] - M)
                          + sa[2] * __expf(pa[2] - M) + sa[3] * __expf(pa[3] - M)
                          + sb[0] * __expf(pb[0] - M) + sb[1] * __expf(pb[1] - M)
                          + sb[2] * __expf(pb[2] - M) + sb[3] * __expf(pb[3] - M);
            const float own = redA[row * 8 + wave];
            const float alpha = __expf(own - M) / S;
#pragma unroll
            for (int c = 0; c < 4; ++c) {
                const int col = c * 128 + wave * 16 + l16;
                Ps[row * PSTR + col] = (short)f2h(acc[c][i][r] * alpha);
            }
        }
    LGKM0(); BARR();

    // ---- t[q][l] = sum_k attn * em_bit_l, packed-f16 mask FMA ----
    {
        const int row = tid >> 4, l = (tid >> 1) & 7, half = tid & 1;
        const uint4* pw = (const uint4*)(Pk + (size_t)(b * LQ + q0 + row) * LK + half * 256);
        const uint4* aw = (const uint4*)&Ps[row * PSTR + half * 256];
        float tv = 0.f;
#pragma unroll 4
        for (int kk = 0; kk < 32; ++kk) {
            const uint4 wb = pw[kk];
            const uint4 av = aw[kk];
            const unsigned w4[4] = {wb.x, wb.y, wb.z, wb.w};
            const unsigned a4[4] = {av.x, av.y, av.z, av.w};
            f16x2 hacc = {(_Float16)0.f, (_Float16)0.f};
#pragma unroll
            for (int u = 0; u < 4; ++u) {
                const unsigned bits = (w4[u] >> l) & 0x10001u;
                const unsigned msk = bits * 0x3c00u;
                hacc += __builtin_bit_cast(f16x2, a4[u]) * __builtin_bit_cast(f16x2, msk);
            }
            tv += (float)hacc[0] + (float)hacc[1];
        }
        tv += __shfl_xor(tv, 1, 64);
        if (half == 0) tS[row * 8 + l] = tv;
    }

    // ================= V pipeline =================
    f32x4 oacc = zz;
    const int mi = wave & 1, ni = wave >> 1;
    WAITVM(0); LGKM0(); BARR();
    COMPUTE_V(0, 0);
    BARR();
    STAGE_V(2, 0);
    WAITVM(2); LGKM0(); BARR();
    COMPUTE_V(1, 1);
    BARR();
    STAGE_V(3, 1);
    WAITVM(2); LGKM0(); BARR();
    COMPUTE_V(2, 0);
    WAITVM(0); LGKM0(); BARR();
    COMPUTE_V(3, 1);

    // ---- output epilogue: + qvr, store Hb bf16 ----
    const int gd = ni * 16 + l16;
    float bvv[NL];
#pragma unroll
    for (int l = 0; l < NL; ++l) bvv[l] = b_vs[l * DQ + gd];
#pragma unroll
    for (int r = 0; r < 4; ++r) {
        const int row = mi * 16 + quad * 4 + r;
        const float* tp = &tS[row * 8];
        float o = oacc[r];
#pragma unroll
        for (int l = 0; l < NL; ++l) o = fmaf(tp[l], bvv[l], o);
        Hb[(size_t)(b * LQ + q0 + row) * DM + h * DQ + gd] = f2bf(o);
    }
}

// ---------------------------------------------------------------------------
// Output projection: Hb(bf16, staged as before) @ w_h_w(fp32, staged fp32 +
// cvt-on-read)^T + bias, fp32 store.  3 gld16/wave/step -> WAITVM(3).
// ---------------------------------------------------------------------------
__global__ __launch_bounds__(256) void outproj(const unsigned short* __restrict__ Hb,
                                               const float* __restrict__ wh,
                                               const float* __restrict__ bias,
                                               float* __restrict__ C) {
    __shared__ __align__(16) short As[2][2048];   // 8 KB  (bf16 A)
    __shared__ __align__(16) float Bs[2][2048];   // 16 KB (fp32 B)
    const int tid = threadIdx.x;
    const int wave = tid >> 6, lane = tid & 63;
    const int quad = lane >> 4, l16 = lane & 15;
    const int wr = wave >> 1, wc = wave & 1;
    const int m0 = blockIdx.x * 64, n0 = blockIdx.y * 64;
    f32x4 acc[2][2];
    const f32x4 zz = {0.f, 0.f, 0.f, 0.f};
#pragma unroll
    for (int i = 0; i < 2; ++i)
#pragma unroll
        for (int j = 0; j < 2; ++j) acc[i][j] = zz;
    const unsigned short* Arp = Hb + (size_t)(m0 + (tid >> 2)) * DM + (tid & 3) * 8;
    const float* Bgp = wh + (size_t)n0 * DM;
    gld16(Arp, (char*)As + wave * 1024);
    STG_FF(Bgp, (char*)Bs, 0);
#pragma unroll
    for (int s = 0; s < 16; ++s) {
        if (s < 15) {
            const int nb = (s + 1) & 1;
            gld16(Arp + (s + 1) * 32, (char*)As + nb * 4096 + wave * 1024);
            STG_FF(Bgp, (char*)Bs + nb * 8192, (s + 1) * 32);
            WAITVM(3);
        } else {
            WAITVM(0);
        }
        BARR();
        const int cb = s & 1;
        const float* Bf = &Bs[0][0] + cb * 2048;
        bf16x8 af[2], bf[2];
#pragma unroll
        for (int i = 0; i < 2; ++i)
            af[i] = *(const bf16x8*)&As[cb][(wr * 32 + i * 16 + l16) * 32 + quad * 8];
#pragma unroll
        for (int j = 0; j < 2; ++j)
            bf[j] = ldfrag_f32(Bf, wc * 32 + j * 16 + l16, quad);
#pragma unroll
        for (int i = 0; i < 2; ++i)
#pragma unroll
            for (int j = 0; j < 2; ++j)
                acc[i][j] = __builtin_amdgcn_mfma_f32_16x16x32_bf16(af[i], bf[j], acc[i][j], 0, 0, 0);
        BARR();
    }
#pragma unroll
    for (int i = 0; i < 2; ++i)
#pragma unroll
        for (int r = 0; r < 4; ++r) {
            const int gm = m0 + wr * 32 + i * 16 + quad * 4 + r;
#pragma unroll
            for (int j = 0; j < 2; ++j) {
                const int gn = n0 + wc * 32 + j * 16 + l16;
                C[(size_t)gm * DM + gn] = acc[i][j][r] + bias[gn];
            }
        }
}

// ---------------------------------------------------------------------------
extern "C" void kernel_launch(void* const* d_in, const int* in_sizes, int n_in,
                              void* d_out, int out_size, void* d_ws, size_t ws_size,
                              hipStream_t stream) {
    const float* q     = (const float*)d_in[0];
    const float* k     = (const float*)d_in[1];
    const float* em    = (const float*)d_in[2];
    const float* pad   = (const float*)d_in[3];
    const float* w_q_w = (const float*)d_in[4];
    const float* w_q_b = (const float*)d_in[5];
    const float* w_k   = (const float*)d_in[6];
    const float* w_v   = (const float*)d_in[7];
    const float* w_h_w = (const float*)d_in[8];
    const float* w_h_b = (const float*)d_in[9];
    const float* b_ks  = (const float*)d_in[10];
    const float* b_vs  = (const float*)d_in[11];

    float* out     = (float*)d_out;                       // (B, LQ, DM) fp32
    float* weights = out + (size_t)NB * LQ * DM;          // (H*B, LQ, LK) fp32

    char* ws = (char*)d_ws;
    unsigned short* Qp = (unsigned short*)(ws + 0);           // 2 MB bf16
    unsigned short* Kp = (unsigned short*)(ws + 2097152);     // 2 MB bf16
    unsigned short* Vt = (unsigned short*)(ws + 4194304);     // 2 MB f16 [b][d][k]
    unsigned short* Hb = (unsigned short*)(ws + 6291456);     // 2 MB bf16
    unsigned short* Pk = (unsigned short*)(ws + 8388608);     // 2 MB 9-bit packs

    front<<<dim3(32, 8, 4), 256, 0, stream>>>(q, k, w_q_w, w_k, w_v, w_q_b,
                                              em, pad, Qp, Kp, Vt, Pk);
    attn_fused<<<dim3(LQ / QT, 32), 512, 0, stream>>>(Qp, Kp, Vt, Pk, b_ks, b_vs, weights, Hb);
    outproj<<<dim3(32, 8), 256, 0, stream>>>(Hb, w_h_w, w_h_b, out);
}